// Round 8
// baseline (129.006 us; speedup 1.0000x reference)
//
#include <hip/hip_runtime.h>
#include <math.h>

#define EPSF 1e-7f
constexpr int NN  = 100;   // nodes per graph
constexpr int DEG = 99;    // fully-connected: deg = NN-1
constexpr int IN  = 6;
constexpr int H   = 128;
constexpr int G   = 8;     // nodes per block (R22: was 4)
constexpr int BPG = 13;    // blocks per graph: 12x8 + 1x4 (ragged tail)
constexpr float INV_PI = 0.3183098861837907f;
constexpr float LOG2E  = 1.4426950408889634f;
constexpr float LN2    = 0.6931471805599453f;

typedef __attribute__((ext_vector_type(4))) _Float16 half4;
typedef __attribute__((ext_vector_type(8))) _Float16 half8;
typedef __attribute__((ext_vector_type(4))) float f32x4;

constexpr int XST = 144;   // fp16 activation stride (288B rows: 16B-aligned)
constexpr int SXS = 15;    // sxr stride in floats: gcd(15,32)=1 -> conflict-free
constexpr int TS  = 50;    // compact tile stride in half4: 48 live + zero slot @48
constexpr int NT  = 50;    // 50 tiles: nodes 0-3 in t0..24, nodes 4-7 in t25..49

__device__ __forceinline__ float clampf(float x, float lo, float hi) {
    return fminf(fmaxf(x, lo), hi);
}
// sigmoid in exp2-space: input y = x*log2e, sig = 1/(1+2^-y).
// R17 post-mortem: poly replacement REGRESSED badly; keep exp2+rcp.
__device__ __forceinline__ float sig2(float y) {
    return __builtin_amdgcn_rcpf(1.f + __builtin_amdgcn_exp2f(-y));
}
// fast atan2: octant-reduced deg-7 minimax (~1e-5 rad; features are fp16)
__device__ __forceinline__ float fast_atan2(float y, float x) {
    float ax = fabsf(x), ay = fabsf(y);
    float mx = fmaxf(ax, ay), mn = fminf(ax, ay);
    float r = mn * __builtin_amdgcn_rcpf(fmaxf(mx, 1e-35f));
    float r2 = r * r;
    float p = fmaf(r2, -0.0851330f, 0.1801410f);
    p = fmaf(r2, p, -0.3302995f);
    p = fmaf(r2, p, 0.9998660f);
    float t = r * p;
    t = (ay > ax) ? (1.5707963267948966f - t) : t;
    t = (x < 0.f) ? (3.14159265358979323f - t) : t;
    return copysignf(t, y);
}
__device__ __forceinline__ float fast_asin(float z) {
    return fast_atan2(z, sqrtf(fmaxf(0.f, (1.f - z) * (1.f + z))));
}
__device__ __forceinline__ float fast_acos(float z) {
    return fast_atan2(sqrtf(fmaxf(0.f, (1.f - z) * (1.f + z))), z);
}
__device__ __forceinline__ void vel_to_R(float vx, float vy, float vz, float* R) {
    float rho = sqrtf(vx * vx + vy * vy + vz * vz);
    float rxy = sqrtf(vx * vx + vy * vy);
    float inv = __builtin_amdgcn_rcpf(rxy);
    bool big = rxy > 1e-30f;
    float ct = big ? vx * inv : 1.f;
    float st = big ? vy * inv : 0.f;
    float cp = clampf(vz * __builtin_amdgcn_rcpf(rho + EPSF), -1.f, 1.f);
    float sp = sqrtf(fmaxf(0.f, 1.f - cp * cp));
    R[0] = cp * ct; R[1] = -st; R[2] = sp * ct;
    R[3] = cp * st; R[4] = ct;  R[5] = sp * st;
    R[6] = -sp;     R[7] = 0.f; R[8] = cp;
}

// ---------------- Kernel A: weights -> fp16 MFMA fragments in ws.
// W1 pre-scaled by log2e (silu in exp2 space); W2 pre-scaled by ln2 to undo.
__global__ void conv_w(const float* __restrict__ W1, const float* __restrict__ W2,
                       const float* __restrict__ W3, const float* __restrict__ W4,
                       half4* __restrict__ w1f, half8* __restrict__ wmlp) {
    int t = blockIdx.x * blockDim.x + threadIdx.x;
    if (t >= 104 * 64) return;
    int L = t & 63, f = t >> 6;
    int m = L & 15, qd = L >> 4;
    if (f < 8) {                          // W1 fragments (K=16, k<12 live)
        int n = f * 16 + m;
        half4 v;
#pragma unroll
        for (int j = 0; j < 4; ++j) {
            int k = qd * 4 + j;
            v[j] = (k < 12) ? (_Float16)(W1[k * H + n] * LOG2E) : (_Float16)0.f;
        }
        w1f[f * 64 + L] = v;
    } else {                              // node-MLP weight fragments (K=32)
        int ff = f - 8;
        int layer = ff >> 5, rest = ff & 31;
        int kt = rest >> 3, nt = rest & 7;
        const float* W = (layer == 0) ? W2 : (layer == 1) ? W3 : W4;
        float scale = (layer == 0) ? LN2 : 1.f;
        int n = nt * 16 + m;
        half8 v;
#pragma unroll
        for (int j = 0; j < 8; ++j)
            v[j] = (_Float16)(W[(kt * 32 + qd * 8 + j) * H + n] * scale);
        wmlp[((layer * 4 + kt) * 8 + nt) * 64 + L] = v;
    }
}

// ---------------- Kernel B: fully fused LoCS layer. One block = 8 nodes.
// R22: double nodes-per-block (G=8, 512 threads, 8 waves). Per-wave work
// unchanged (1 channel-tile x 50 tiles = same 200 silu elems); per-NODE fixed
// costs halve: MLP weight L2 traffic 307->154 MB, node-table build 25x->12.5x
// redundancy, tail phases amortized over 8 nodes. R18/R19/R21 showed the
// schedule is not the bottleneck; this attacks block-count-scaled overhead.
// 13 blocks/graph; last block ragged (4 nodes): zero tiles are benign
// (d=bias, finite), outputs guarded by g<cnt.
__global__ __launch_bounds__(512, 8)
void locs_fused(const float* __restrict__ in,
                const float* __restrict__ W1, const float* __restrict__ b1,
                const float* __restrict__ b2,
                const float* __restrict__ Wr, const float* __restrict__ br,
                const float* __restrict__ b3, const float* __restrict__ b4,
                const float* __restrict__ W5, const float* __restrict__ b5,
                const half4* __restrict__ w1f, const half8* __restrict__ wmlp,
                float* __restrict__ out) {
    __shared__ _Float16 hpool[NT * TS * 4];      // arena (20 KB); xh0/xh1 live here
    __shared__ float sxr[NN * SXS];              // per-node R(9)+pos(3)+vel(3)
    __shared__ float cvF[32];                    // canon_vel per node (8 nodes)
    __shared__ float pbF[G * 96];                // W5 partials
    __shared__ float predF[G * 8];

    const int tid = threadIdx.x;
    const int L   = tid & 63;
    const int wv  = tid >> 6;                    // wave 0..7
    const int q   = L >> 4;                      // lane quad == node row group / kslot
    const int lm  = L & 15;
    const int bB   = blockIdx.x / BPG;           // graph index
    const int blkg = blockIdx.x - bB * BPG;
    const int n0   = blkg * G;                   // first node in graph (0..96)
    const int cnt  = (NN - n0 < G) ? (NN - n0) : G;   // 8, or 4 for last block

    _Float16* xh0 = hpool;                       // ping-pong activation buffers
    _Float16* xh1 = hpool + G * XST;             // rows 0..7

    // ---- setup: zero arena (pad rows / zero slots stay zero all launch)
    {
        half4 z = {0, 0, 0, 0};
        for (int i = tid; i < NT * TS; i += 512) *(half4*)&hpool[i * 4] = z;
    }
    // ragged block: zero the cvF tail (nodes cnt..7) -- owners never write it
    if (tid >= cnt * 4 && tid < 32) cvF[tid] = 0.f;
    // per-graph-node table (one vel_to_R per node, stride 15 = conflict-free).
    // The threads owning this block's nodes also emit canon_vel from regs.
    if (tid < NN) {
        const float* xi = in + (bB * NN + tid) * IN;
        float R[9];
        float px = xi[0], py = xi[1], pz = xi[2];
        float vx = xi[3], vy = xi[4], vz = xi[5];
        vel_to_R(vx, vy, vz, R);
        float* dst = sxr + tid * SXS;
#pragma unroll
        for (int k = 0; k < 9; ++k) dst[k] = R[k];
        dst[9] = px; dst[10] = py; dst[11] = pz;
        dst[12] = vx; dst[13] = vy; dst[14] = vz;
        int g = tid - n0;
        if ((unsigned)g < (unsigned)cnt) {
            cvF[g * 4 + 0] = R[0] * vx + R[3] * vy + R[6] * vz;
            cvF[g * 4 + 1] = R[1] * vx + R[4] * vy + R[7] * vz;
            cvF[g * 4 + 2] = R[2] * vx + R[5] * vy + R[8] * vz;
        }
    }
    __syncthreads();                             // sxr + cvF visible

    // folded silu bias (exp2 space) for this lane's channel, both node groups
    // (node q for tiles 0..24, node q+4 for tiles 25..49). 4 global loads
    // serve both. Issued before the producer to hide latency.
    float bsA, bsB;
    {
        int ch = wv * 16 + lm;
        float w15 = W1[15 * H + ch], w16 = W1[16 * H + ch], w17 = W1[17 * H + ch];
        float bb = b1[ch];
        bsA = (bb + cvF[q * 4 + 0] * w15 + cvF[q * 4 + 1] * w16
             + cvF[q * 4 + 2] * w17) * LOG2E;
        bsB = (bb + cvF[(q + 4) * 4 + 0] * w15 + cvF[(q + 4) * 4 + 1] * w16
             + cvF[(q + 4) * 4 + 2] * w17) * LOG2E;
    }
    // W1 B-fragment (this wave's channel-tile)
    half4 bfr = w1f[wv * 64 + L];

    // ---- dense producer: all live nodes' edge features, packed compact layout
#pragma unroll
    for (int rnd = 0; rnd < 2; ++rnd) {
        int j = tid + rnd * 512;
        if (j < cnt * DEG) {
            int g = j / DEG;                     // owning node 0..7
            int e = j - g * DEG;                 // edge index 0..98
            int nG = n0 + g;
            int s = e < nG ? e : e + 1;          // implicit ~eye edge list
            const float* rn = sxr + nG * SXS;
            const float* rs = sxr + s * SXS;     // stride-15: conflict-free
            float Rn[9];
#pragma unroll
            for (int k = 0; k < 9; ++k) Rn[k] = rn[k];
            float rel0 = rs[9] - rn[9], rel1 = rs[10] - rn[10], rel2 = rs[11] - rn[11];
            float vjx = rs[12], vjy = rs[13], vjz = rs[14];
            float Rs0 = rs[0], Rs1 = rs[1], Rs2 = rs[2];
            float Rs3 = rs[3], Rs4 = rs[4], Rs5 = rs[5];
            float Rs6 = rs[6], Rs7 = rs[7], Rs8 = rs[8];
            float rr0 = Rn[0] * rel0 + Rn[3] * rel1 + Rn[6] * rel2;
            float rr1 = Rn[1] * rel0 + Rn[4] * rel1 + Rn[7] * rel2;
            float rr2 = Rn[2] * rel0 + Rn[5] * rel1 + Rn[8] * rel2;
            float ro00 = Rn[0] * Rs0 + Rn[3] * Rs3 + Rn[6] * Rs6;
            float ro10 = Rn[1] * Rs0 + Rn[4] * Rs3 + Rn[7] * Rs6;
            float ro20 = Rn[2] * Rs0 + Rn[5] * Rs3 + Rn[8] * Rs6;
            float ro21 = Rn[2] * Rs1 + Rn[5] * Rs4 + Rn[8] * Rs7;
            float ro22 = Rn[2] * Rs2 + Rn[5] * Rs5 + Rn[8] * Rs8;
            float dist = sqrtf(rel0 * rel0 + rel1 * rel1 + rel2 * rel2);
            half4 f0, f1, f2;
            f0[0] = (_Float16)rr0; f0[1] = (_Float16)rr1; f0[2] = (_Float16)rr2;
            f0[3] = (_Float16)(fast_atan2(ro10, ro00) * INV_PI);
            f1[0] = (_Float16)(fast_asin(clampf(-ro20, -1.f, 1.f)) * INV_PI);
            f1[1] = (_Float16)(fast_atan2(ro21, ro22) * INV_PI);
            f1[2] = (_Float16)dist;              // |rot_rel| == |rel|
            f1[3] = (_Float16)fast_atan2(rr1, rr0);
            f2[0] = (_Float16)fast_acos(clampf(rr2 * __builtin_amdgcn_rcpf(dist + EPSF), -1.f, 1.f));
            f2[1] = (_Float16)(Rn[0] * vjx + Rn[3] * vjy + Rn[6] * vjz);
            f2[2] = (_Float16)(Rn[1] * vjx + Rn[4] * vjy + Rn[7] * vjz);
            f2[3] = (_Float16)(Rn[2] * vjx + Rn[5] * vjy + Rn[8] * vjz);
            int t = (e >> 2) + (g >> 2) * 25;    // tile (node-group in t>=25)
            int mrow = (g & 3) * 4 + (e & 3);    // A row: node quad + edge%4
            _Float16* dst = hpool + (t * TS + mrow) * 4;
            *(half4*)(dst +   0)      = f0;      // kslot 0
            *(half4*)(dst + 16 * 4)   = f1;      // kslot 1
            *(half4*)(dst + 32 * 4)   = f2;      // kslot 2 (kslot 3 = zeros)
        }
    }
    __syncthreads();

    // ---- consumer: 2 groups x 25-tile MFMA + silu, software-pipelined.
    // 8 waves each own 1 channel-tile; group 0 = nodes 0-3, group 1 = nodes 4-7.
    {
        float part[2] = {0.f, 0.f};
        const float bsv[2] = {bsA, bsB};
        const int loff = (q < 3) ? (q * 16 + lm) : 48;   // qd==3 -> zero slot
#pragma unroll
        for (int grp = 0; grp < 2; ++grp) {
            f32x4 c = (f32x4){bsv[grp], bsv[grp], bsv[grp], bsv[grp]};
            const int tb = grp * 25;
            half4 a_cur = *(const half4*)&hpool[(tb * TS + loff) * 4];
#pragma unroll
            for (int t = 0; t < 25; ++t) {
                half4 a_next;
                if (t < 24) a_next = *(const half4*)&hpool[((tb + t + 1) * TS + loff) * 4];
                f32x4 d = __builtin_amdgcn_mfma_f32_16x16x16f16(a_cur, bfr, c, 0, 0, 0);
#pragma unroll
                for (int r = 0; r < 4; ++r) part[grp] += d[r] * sig2(d[r]);
                a_cur = a_next;
            }
        }
        __syncthreads();                 // ALL waves' tile reads done (xh0 aliases tiles)
        // exactly one pad element per node (t=24/49, r=3): cancel uniformly
        int ch = wv * 16 + lm;
        xh0[q * XST + ch]       = (_Float16)(part[0] - bsA * sig2(bsA));
        xh0[(q + 4) * XST + ch] = (_Float16)(part[1] - bsB * sig2(bsB));
    }
    __syncthreads();                             // xh0 visible

    // ---- node MLP: 3 layers, fp16 MFMA, ping-pong xh0/xh1 (1 barrier/layer)
#pragma unroll
    for (int layer = 0; layer < 3; ++layer) {
        const _Float16* src = (layer & 1) ? xh1 : xh0;
        _Float16*       dst = (layer & 1) ? xh0 : xh1;
        // this wave's 4 weight fragments (independent -> 4 outstanding L2 reqs)
        half8 bh[4];
#pragma unroll
        for (int kt = 0; kt < 4; ++kt)
            bh[kt] = wmlp[((layer * 4 + kt) * 8 + wv) * 64 + L];
        int rowb = (lm & 7) * XST;        // rows 8..15 read dup rows (unused outputs)
        half8 ah[4];
#pragma unroll
        for (int kt = 0; kt < 4; ++kt)
            ah[kt] = *(const half8*)&src[rowb + kt * 32 + q * 8];
        f32x4 acc = (f32x4){0.f, 0.f, 0.f, 0.f};
#pragma unroll
        for (int kt = 0; kt < 4; ++kt)
            acc = __builtin_amdgcn_mfma_f32_16x16x32_f16(ah[kt], bh[kt], acc, 0, 0, 0);
        // dst != src: no post-read barrier needed before writing
        if (L < 32) {                     // lanes 0..31 hold rows 0..7 (the 8 nodes)
            int ch = wv * 16 + lm;
            if (layer == 0) {
                float b2c = b2[ch], brc = br[ch];
                float w3c = Wr[3 * H + ch], w4c = Wr[4 * H + ch], w5c = Wr[5 * H + ch];
#pragma unroll
                for (int r = 0; r < 4; ++r) {
                    int rr = q * 4 + r;
                    dst[rr * XST + ch] = (_Float16)(acc[r] * (1.f / 99.f) + b2c
                                      + cvF[rr * 4 + 0] * w3c + cvF[rr * 4 + 1] * w4c
                                      + cvF[rr * 4 + 2] * w5c + brc);
                }
            } else {
                float bb = (layer == 1) ? b3[ch] : b4[ch];
#pragma unroll
                for (int r = 0; r < 4; ++r) {
                    int rr = q * 4 + r;
                    dst[rr * XST + ch] = (_Float16)fmaxf(0.f, acc[r] + bb);
                }
            }
        }
        __syncthreads();                  // dst visible for next layer
    }

    // ---- pred = p2 @ W5 + b5, then rotate + residual (p2 lives in xh1)
    if (tid < 96) {
        int o = tid >> 4, sl = tid & 15, kb = sl * 8;
        float w5[8];
#pragma unroll
        for (int j = 0; j < 8; ++j) w5[j] = W5[(kb + j) * IN + o];
#pragma unroll
        for (int g = 0; g < G; ++g) {
            half8 xv = *(const half8*)&xh1[g * XST + kb];
            float s = 0.f;
#pragma unroll
            for (int j = 0; j < 8; ++j) s = fmaf((float)xv[j], w5[j], s);
            pbF[g * 96 + sl * 6 + o] = s;
        }
    }
    __syncthreads();
    if (tid < 48) {
        int g = tid / 6, o = tid - g * 6;
        float s = b5[o];
#pragma unroll
        for (int sl = 0; sl < 16; ++sl) s += pbF[g * 96 + sl * 6 + o];
        predF[g * 8 + o] = s;
    }
    __syncthreads();
    if (tid < 48) {
        int g = tid / 6, o = tid - g * 6;
        if (g < cnt) {
            int r = (o < 3) ? o : o - 3;
            int off = (o < 3) ? 0 : 3;
            const float* Rg = sxr + (n0 + g) * SXS;
            float gl = Rg[r * 3 + 0] * predF[g * 8 + off + 0]
                     + Rg[r * 3 + 1] * predF[g * 8 + off + 1]
                     + Rg[r * 3 + 2] * predF[g * 8 + off + 2];
            int bng = bB * NN + n0 + g;
            out[bng * IN + o] = Rg[9 + o] + gl;  // in[bng*6+o] == sxr pos/vel
        }
    }
}

extern "C" void kernel_launch(void* const* d_in, const int* in_sizes, int n_in,
                              void* d_out, int out_size, void* d_ws, size_t ws_size,
                              hipStream_t stream) {
    const float* in = (const float*)d_in[0];
    const float* W1 = (const float*)d_in[1];
    const float* b1 = (const float*)d_in[2];
    const float* W2 = (const float*)d_in[3];
    const float* b2 = (const float*)d_in[4];
    const float* Wr = (const float*)d_in[5];
    const float* br = (const float*)d_in[6];
    const float* W3 = (const float*)d_in[7];
    const float* b3 = (const float*)d_in[8];
    const float* W4 = (const float*)d_in[9];
    const float* b4 = (const float*)d_in[10];
    const float* W5 = (const float*)d_in[11];
    const float* b5 = (const float*)d_in[12];
    float* out = (float*)d_out;

    half4* w1f  = (half4*)d_ws;                         // 4 KB
    half8* wmlp = (half8*)((char*)d_ws + 4096);         // 96 KB

    const int BN = in_sizes[0] / IN;   // B*N = 12800
    const int nGraphs = BN / NN;       // 128
    conv_w<<<26, 256, 0, stream>>>(W1, W2, W3, W4, w1f, wmlp);
    locs_fused<<<nGraphs * BPG, 512, 0, stream>>>(in, W1, b1, b2, Wr, br, b3, b4,
                                                  W5, b5, w1f, wmlp, out);
}